// Round 1
// baseline (57786.182 us; speedup 1.0000x reference)
//
#include <hip/hip_runtime.h>
#include <hip/hip_bf16.h>

#define SEQ 2048
#define IN_DIM 2048
#define HID 4096
#define CONCAT 6144
#define OUT_DIM 2048

typedef __attribute__((ext_vector_type(8))) short s8v;
typedef __attribute__((ext_vector_type(4))) float f4v;

// ---------------- ws layout (bytes) ----------------
// Z:     [0, 33554432)            float Z[SEQ][HID]
// hbuf:  [33554432, 67108864)     float hbuf[SEQ][HID]   (rows 1..2047 used)
// Xb:    [33554432, +8388608)     bf16  (overlaps hbuf; consumed by K2 before K3 writes)
// Wxb:   [41943040, +16777216)    bf16
// flags: [67108864, +1024)        int[256]
// total required: 67,109,888 B

// ---------------- K1: pack bf16 + zero flags ----------------
__global__ __launch_bounds__(256) void k1_prep(const float* __restrict__ X,
                                               const float* __restrict__ Wi2h,
                                               __hip_bfloat16* __restrict__ Xb,
                                               __hip_bfloat16* __restrict__ Wxb,
                                               int* __restrict__ flags) {
  int gid = blockIdx.x * blockDim.x + threadIdx.x;
  int stride = gridDim.x * blockDim.x;
  for (int i = gid; i < SEQ * IN_DIM; i += stride)
    Xb[i] = __float2bfloat16(X[i]);
  for (int i = gid; i < HID * IN_DIM; i += stride) {
    int r = i >> 11, c = i & (IN_DIM - 1);
    Wxb[i] = __float2bfloat16(Wi2h[(long long)r * CONCAT + c]);
  }
  if (gid < 256) flags[gid] = 0;
}

// ---------------- K2: Z = Xb @ Wxb^T + b  (bf16 MFMA, 64x64 tiles) ----------------
__global__ __launch_bounds__(256) void k2_zgemm(const __hip_bfloat16* __restrict__ Xb,
                                                const __hip_bfloat16* __restrict__ Wxb,
                                                const float* __restrict__ bias,
                                                float* __restrict__ Z) {
  __shared__ __align__(16) __hip_bfloat16 As[64][40];  // +8 pad: kills ds_read conflicts
  __shared__ __align__(16) __hip_bfloat16 Bs[64][40];
  const int bm = blockIdx.x & 31;   // 32 M-tiles (SEQ/64)
  const int bn = blockIdx.x >> 5;   // 64 N-tiles (HID/64)
  const int tid = threadIdx.x;
  const int wv = tid >> 6, l = tid & 63;
  const int wr = (wv >> 1) * 32, wc = (wv & 1) * 32;   // wave's 32x32 quadrant
  const int fr = l & 15, fko = (l >> 4) * 8;

  f4v acc[2][2] = {};
  const int r = tid >> 2, cc = (tid & 3) * 8;          // staging: row, 8-elem chunk
  const __hip_bfloat16* ga = Xb + (long long)(bm * 64 + r) * IN_DIM + cc;
  const __hip_bfloat16* gb = Wxb + (long long)(bn * 64 + r) * IN_DIM + cc;

  for (int k0 = 0; k0 < IN_DIM; k0 += 32) {
    *(s8v*)&As[r][cc] = *(const s8v*)(ga + k0);
    *(s8v*)&Bs[r][cc] = *(const s8v*)(gb + k0);
    __syncthreads();
    s8v a0 = *(const s8v*)&As[wr + fr][fko];
    s8v a1 = *(const s8v*)&As[wr + 16 + fr][fko];
    s8v b0 = *(const s8v*)&Bs[wc + fr][fko];
    s8v b1 = *(const s8v*)&Bs[wc + 16 + fr][fko];
    acc[0][0] = __builtin_amdgcn_mfma_f32_16x16x32_bf16(a0, b0, acc[0][0], 0, 0, 0);
    acc[0][1] = __builtin_amdgcn_mfma_f32_16x16x32_bf16(a0, b1, acc[0][1], 0, 0, 0);
    acc[1][0] = __builtin_amdgcn_mfma_f32_16x16x32_bf16(a1, b0, acc[1][0], 0, 0, 0);
    acc[1][1] = __builtin_amdgcn_mfma_f32_16x16x32_bf16(a1, b1, acc[1][1], 0, 0, 0);
    __syncthreads();
  }
#pragma unroll
  for (int fm = 0; fm < 2; ++fm)
#pragma unroll
    for (int fn = 0; fn < 2; ++fn)
#pragma unroll
      for (int i = 0; i < 4; ++i) {
        int row = bm * 64 + wr + fm * 16 + (l >> 4) * 4 + i;
        int col = bn * 64 + wc + fn * 16 + fr;
        Z[(long long)row * HID + col] = acc[fm][fn][i] + bias[col];
      }
}

// ---------------- K3: persistent-weight recurrence (cooperative) ----------------
// 256 WGs x 512 thr. WG w owns h rows [16w,16w+16). Wave v owns K-slice [512v,512v+512).
// Lane l: k indices 512v + 64j + l (j=0..7); weights Wreg[16][8] in VGPRs.
__global__ __launch_bounds__(512, 2) void k3_rnn(const float* __restrict__ Wi2h,
                                                 const float* __restrict__ Z,
                                                 float* __restrict__ hbuf,
                                                 int* __restrict__ flags) {
  const int w = blockIdx.x;
  const int tid = threadIdx.x;
  const int v = tid >> 6;
  const int l = tid & 63;
  const int rowbase = w * 16;
  const int kbase = v * 512 + l;

  float Wreg[16][8];
#pragma unroll
  for (int r = 0; r < 16; ++r) {
    const float* src = Wi2h + (long long)(rowbase + r) * CONCAT + IN_DIM + kbase;
#pragma unroll
    for (int j = 0; j < 8; ++j) Wreg[r][j] = src[64 * j];
  }

  __shared__ float part[2][8][16];
  const int lm = l & 15;
  const int r_mine = ((lm & 1) << 3) | ((lm & 2) << 1) | ((lm & 4) >> 1) | ((lm & 8) >> 3);

  for (int t = 0; t < SEQ - 1; ++t) {
    // prefetch z for this WG's rows (independent of h)
    float zv = 0.f;
    if (v == 0 && l < 16) zv = Z[(long long)t * HID + rowbase + l];

    float acc[16];
#pragma unroll
    for (int r = 0; r < 16; ++r) acc[r] = 0.f;

    if (t > 0) {
      // wait for the 32 producer WGs of this wave's K-slice
      const int* fl = flags + 32 * v + (l & 31);
      while (true) {
        int f = __hip_atomic_load(fl, __ATOMIC_RELAXED, __HIP_MEMORY_SCOPE_AGENT);
        if (__all(f >= t)) break;
      }
      __builtin_amdgcn_fence(__ATOMIC_ACQUIRE, "agent");
      const float* hrow = hbuf + (long long)t * HID + kbase;
      float hv[8];
#pragma unroll
      for (int j = 0; j < 8; ++j)
        hv[j] = __hip_atomic_load(hrow + 64 * j, __ATOMIC_RELAXED, __HIP_MEMORY_SCOPE_AGENT);
#pragma unroll
      for (int r = 0; r < 16; ++r)
#pragma unroll
        for (int j = 0; j < 8; ++j)
          acc[r] = fmaf(Wreg[r][j], hv[j], acc[r]);
    }

    // reduce-scatter butterfly: 16 accs across 64 lanes -> 1 row-sum per lane-of-16
#pragma unroll
    for (int i = 0; i < 8; ++i) {
      float send = (l & 1) ? acc[i] : acc[i + 8];
      float keep = (l & 1) ? acc[i + 8] : acc[i];
      acc[i] = keep + __shfl_xor(send, 1, 64);
    }
#pragma unroll
    for (int i = 0; i < 4; ++i) {
      float send = (l & 2) ? acc[i] : acc[i + 4];
      float keep = (l & 2) ? acc[i + 4] : acc[i];
      acc[i] = keep + __shfl_xor(send, 2, 64);
    }
#pragma unroll
    for (int i = 0; i < 2; ++i) {
      float send = (l & 4) ? acc[i] : acc[i + 2];
      float keep = (l & 4) ? acc[i + 2] : acc[i];
      acc[i] = keep + __shfl_xor(send, 4, 64);
    }
    {
      float send = (l & 8) ? acc[0] : acc[1];
      float keep = (l & 8) ? acc[1] : acc[0];
      acc[0] = keep + __shfl_xor(send, 8, 64);
    }
    float rsum = acc[0];
    rsum += __shfl_xor(rsum, 16, 64);
    rsum += __shfl_xor(rsum, 32, 64);

    const int b = t & 1;
    if (l < 16) part[b][v][r_mine] = rsum;
    __syncthreads();

    if (v == 0 && l < 16) {
      float s = 0.f;
#pragma unroll
      for (int q = 0; q < 8; ++q) s += part[b][q][l];
      float pre = s + zv;
      float hn = 1.0f / (1.0f + __expf(-pre));
      __hip_atomic_store(hbuf + (long long)(t + 1) * HID + rowbase + l, hn,
                         __ATOMIC_RELAXED, __HIP_MEMORY_SCOPE_AGENT);
      __threadfence();  // wave-level drain of the 16 h stores
      if (l == 0)
        __hip_atomic_store(flags + w, t + 1, __ATOMIC_RELEASE, __HIP_MEMORY_SCOPE_AGENT);
    }
    // no second __syncthreads: LDS 'part' is double-buffered; waves pipeline into
    // the next step's poll while wave 0 finalizes.
  }
}

// ---------------- K4: out = W_i2o @ [x_last, h_last] + b ----------------
__global__ __launch_bounds__(256) void k4_out(const float* __restrict__ X,
                                              const float* __restrict__ Wi2o,
                                              const float* __restrict__ bi2o,
                                              const float* __restrict__ hbuf,
                                              float* __restrict__ out) {
  const int v = threadIdx.x >> 6, l = threadIdx.x & 63;
  const int o = blockIdx.x * 4 + v;
  const float* wrow = Wi2o + (long long)o * CONCAT;
  const float* xlast = X + (long long)(SEQ - 1) * IN_DIM;
  const float* hlast = hbuf + (long long)(SEQ - 1) * HID;
  float s = 0.f;
  for (int k = l; k < IN_DIM; k += 64) s = fmaf(wrow[k], xlast[k], s);
  for (int k = l; k < HID; k += 64) s = fmaf(wrow[IN_DIM + k], hlast[k], s);
#pragma unroll
  for (int m = 1; m < 64; m <<= 1) s += __shfl_xor(s, m, 64);
  if (l == 0) out[o] = s + bi2o[o];
}

extern "C" void kernel_launch(void* const* d_in, const int* in_sizes, int n_in,
                              void* d_out, int out_size, void* d_ws, size_t ws_size,
                              hipStream_t stream) {
  (void)in_sizes; (void)n_in; (void)out_size; (void)ws_size;
  const float* X    = (const float*)d_in[0];
  const float* Wi2h = (const float*)d_in[1];
  const float* bi2h = (const float*)d_in[2];
  const float* Wi2o = (const float*)d_in[3];
  const float* bi2o = (const float*)d_in[4];
  float* out = (float*)d_out;

  char* ws = (char*)d_ws;
  float* Z              = (float*)(ws);
  float* hbuf           = (float*)(ws + 33554432);
  __hip_bfloat16* Xb    = (__hip_bfloat16*)(ws + 33554432);  // overlaps hbuf (safe: stream order)
  __hip_bfloat16* Wxb   = (__hip_bfloat16*)(ws + 41943040);
  int* flags            = (int*)(ws + 67108864);

  hipLaunchKernelGGL(k1_prep, dim3(2048), dim3(256), 0, stream, X, Wi2h, Xb, Wxb, flags);
  hipLaunchKernelGGL(k2_zgemm, dim3(2048), dim3(256), 0, stream, Xb, Wxb, bi2h, Z);

  void* args[] = { (void*)&Wi2h, (void*)&Z, (void*)&hbuf, (void*)&flags };
  hipLaunchCooperativeKernel((void*)k3_rnn, dim3(256), dim3(512), args, 0, stream);

  hipLaunchKernelGGL(k4_out, dim3(512), dim3(256), 0, stream, X, Wi2o, bi2o, hbuf, out);
}

// Round 2
// 10385.883 us; speedup vs baseline: 5.5639x; 5.5639x over previous
//
#include <hip/hip_runtime.h>
#include <hip/hip_bf16.h>

#define SEQ 2048
#define IN_DIM 2048
#define HID 4096
#define CONCAT 6144
#define OUT_DIM 2048

typedef __attribute__((ext_vector_type(8))) short s8v;
typedef __attribute__((ext_vector_type(4))) float f4v;

// ---------------- ws layout (bytes) ----------------
// Z:     [0, 33554432)            float Z[SEQ][HID]
// hbuf:  [33554432, 67108864)     float hbuf[SEQ][HID]   (rows 1..2047 used)
// Xb:    [33554432, +8388608)     bf16  (overlaps hbuf; consumed by K2 before K3 writes)
// Wxb:   [41943040, +16777216)    bf16
// flags: [67108864, +1024)        int[256]
// total required: 67,109,888 B

// ---------------- K1: pack bf16 + zero flags ----------------
__global__ __launch_bounds__(256) void k1_prep(const float* __restrict__ X,
                                               const float* __restrict__ Wi2h,
                                               __hip_bfloat16* __restrict__ Xb,
                                               __hip_bfloat16* __restrict__ Wxb,
                                               int* __restrict__ flags) {
  int gid = blockIdx.x * blockDim.x + threadIdx.x;
  int stride = gridDim.x * blockDim.x;
  for (int i = gid; i < SEQ * IN_DIM; i += stride)
    Xb[i] = __float2bfloat16(X[i]);
  for (int i = gid; i < HID * IN_DIM; i += stride) {
    int r = i >> 11, c = i & (IN_DIM - 1);
    Wxb[i] = __float2bfloat16(Wi2h[(long long)r * CONCAT + c]);
  }
  if (gid < 256) flags[gid] = 0;
}

// ---------------- K2: Z = Xb @ Wxb^T + b  (bf16 MFMA, 64x64 tiles) ----------------
__global__ __launch_bounds__(256) void k2_zgemm(const __hip_bfloat16* __restrict__ Xb,
                                                const __hip_bfloat16* __restrict__ Wxb,
                                                const float* __restrict__ bias,
                                                float* __restrict__ Z) {
  __shared__ __align__(16) __hip_bfloat16 As[64][40];  // +8 pad: kills ds_read conflicts
  __shared__ __align__(16) __hip_bfloat16 Bs[64][40];
  const int bm = blockIdx.x & 31;   // 32 M-tiles (SEQ/64)
  const int bn = blockIdx.x >> 5;   // 64 N-tiles (HID/64)
  const int tid = threadIdx.x;
  const int wv = tid >> 6, l = tid & 63;
  const int wr = (wv >> 1) * 32, wc = (wv & 1) * 32;   // wave's 32x32 quadrant
  const int fr = l & 15, fko = (l >> 4) * 8;

  f4v acc[2][2] = {};
  const int r = tid >> 2, cc = (tid & 3) * 8;          // staging: row, 8-elem chunk
  const __hip_bfloat16* ga = Xb + (long long)(bm * 64 + r) * IN_DIM + cc;
  const __hip_bfloat16* gb = Wxb + (long long)(bn * 64 + r) * IN_DIM + cc;

  for (int k0 = 0; k0 < IN_DIM; k0 += 32) {
    *(s8v*)&As[r][cc] = *(const s8v*)(ga + k0);
    *(s8v*)&Bs[r][cc] = *(const s8v*)(gb + k0);
    __syncthreads();
    s8v a0 = *(const s8v*)&As[wr + fr][fko];
    s8v a1 = *(const s8v*)&As[wr + 16 + fr][fko];
    s8v b0 = *(const s8v*)&Bs[wc + fr][fko];
    s8v b1 = *(const s8v*)&Bs[wc + 16 + fr][fko];
    acc[0][0] = __builtin_amdgcn_mfma_f32_16x16x32_bf16(a0, b0, acc[0][0], 0, 0, 0);
    acc[0][1] = __builtin_amdgcn_mfma_f32_16x16x32_bf16(a0, b1, acc[0][1], 0, 0, 0);
    acc[1][0] = __builtin_amdgcn_mfma_f32_16x16x32_bf16(a1, b0, acc[1][0], 0, 0, 0);
    acc[1][1] = __builtin_amdgcn_mfma_f32_16x16x32_bf16(a1, b1, acc[1][1], 0, 0, 0);
    __syncthreads();
  }
#pragma unroll
  for (int fm = 0; fm < 2; ++fm)
#pragma unroll
    for (int fn = 0; fn < 2; ++fn)
#pragma unroll
      for (int i = 0; i < 4; ++i) {
        int row = bm * 64 + wr + fm * 16 + (l >> 4) * 4 + i;
        int col = bn * 64 + wc + fn * 16 + fr;
        Z[(long long)row * HID + col] = acc[fm][fn][i] + bias[col];
      }
}

// ---------------- K3: persistent-weight recurrence (cooperative) ----------------
// 256 WGs x 512 thr. WG w owns h rows [16w,16w+16). Wave v owns K-slice [512v,512v+512).
// Lane l: k indices 512v + 64j + l (j=0..7); weights Wreg[16][8] pinned in VGPRs.
// Sync discipline: ALL cross-WG traffic is relaxed agent-scope atomics (sc1 ->
// bypass L1/L2, coherence point = IF$). NO fences in the loop: producer does
// h-stores, s_waitcnt vmcnt(0), flag store; consumer polls flag then loads h
// (data/control dependence orders the issue). Zero cache-maintenance ops.
__global__ __launch_bounds__(512, 1) void k3_rnn(const float* __restrict__ Wi2h,
                                                 const float* __restrict__ Z,
                                                 float* __restrict__ hbuf,
                                                 int* __restrict__ flags) {
  const int w = blockIdx.x;
  const int tid = threadIdx.x;
  const int v = tid >> 6;
  const int l = tid & 63;
  const int rowbase = w * 16;
  const int kbase = v * 512 + l;

  float Wreg[16][8];
#pragma unroll
  for (int r = 0; r < 16; ++r) {
    const float* src = Wi2h + (long long)(rowbase + r) * CONCAT + IN_DIM + kbase;
#pragma unroll
    for (int j = 0; j < 8; ++j) Wreg[r][j] = src[64 * j];
  }
  // pin weights into registers: opaque identity so the compiler can neither
  // rematerialize from memory nor sink the loads into the t-loop
#pragma unroll
  for (int r = 0; r < 16; ++r)
#pragma unroll
    for (int j = 0; j < 8; ++j)
      asm volatile("" : "+v"(Wreg[r][j]));

  __shared__ float part[2][8][16];
  const int lm = l & 15;
  const int r_mine = ((lm & 1) << 3) | ((lm & 2) << 1) | ((lm & 4) >> 1) | ((lm & 8) >> 3);

  for (int t = 0; t < SEQ - 1; ++t) {
    // prefetch z for this WG's rows (independent of h)
    float zv = 0.f;
    if (v == 0 && l < 16) zv = Z[(long long)t * HID + rowbase + l];

    float acc[16];
#pragma unroll
    for (int r = 0; r < 16; ++r) acc[r] = 0.f;

    if (t > 0) {
      // wait for the 32 producer WGs of this wave's K-slice
      const int* fl = flags + 32 * v + (l & 31);
      while (true) {
        int f = __hip_atomic_load(fl, __ATOMIC_RELAXED, __HIP_MEMORY_SCOPE_AGENT);
        if (__all(f >= t)) break;
        __builtin_amdgcn_s_sleep(1);  // throttle spin traffic to IF$
      }
      asm volatile("" ::: "memory");  // compiler-only barrier: h loads stay below poll
      const float* hrow = hbuf + (long long)t * HID + kbase;
      float hv[8];
#pragma unroll
      for (int j = 0; j < 8; ++j)
        hv[j] = __hip_atomic_load(hrow + 64 * j, __ATOMIC_RELAXED, __HIP_MEMORY_SCOPE_AGENT);
#pragma unroll
      for (int r = 0; r < 16; ++r)
#pragma unroll
        for (int j = 0; j < 8; ++j)
          acc[r] = fmaf(Wreg[r][j], hv[j], acc[r]);
    }

    // reduce-scatter butterfly: 16 accs across 64 lanes -> 1 row-sum per lane-of-16
#pragma unroll
    for (int i = 0; i < 8; ++i) {
      float send = (l & 1) ? acc[i] : acc[i + 8];
      float keep = (l & 1) ? acc[i + 8] : acc[i];
      acc[i] = keep + __shfl_xor(send, 1, 64);
    }
#pragma unroll
    for (int i = 0; i < 4; ++i) {
      float send = (l & 2) ? acc[i] : acc[i + 4];
      float keep = (l & 2) ? acc[i + 4] : acc[i];
      acc[i] = keep + __shfl_xor(send, 2, 64);
    }
#pragma unroll
    for (int i = 0; i < 2; ++i) {
      float send = (l & 4) ? acc[i] : acc[i + 2];
      float keep = (l & 4) ? acc[i + 2] : acc[i];
      acc[i] = keep + __shfl_xor(send, 4, 64);
    }
    {
      float send = (l & 8) ? acc[0] : acc[1];
      float keep = (l & 8) ? acc[1] : acc[0];
      acc[0] = keep + __shfl_xor(send, 8, 64);
    }
    float rsum = acc[0];
    rsum += __shfl_xor(rsum, 16, 64);
    rsum += __shfl_xor(rsum, 32, 64);

    const int b = t & 1;
    if (l < 16) part[b][v][r_mine] = rsum;
    __syncthreads();

    if (v == 0 && l < 16) {
      float s = 0.f;
#pragma unroll
      for (int q = 0; q < 8; ++q) s += part[b][q][l];
      float pre = s + zv;
      float hn = 1.0f / (1.0f + __expf(-pre));
      __hip_atomic_store(hbuf + (long long)(t + 1) * HID + rowbase + l, hn,
                         __ATOMIC_RELAXED, __HIP_MEMORY_SCOPE_AGENT);
      // order h stores (this wave's vmem) before the flag store; no cache ops
      asm volatile("s_waitcnt vmcnt(0)" ::: "memory");
      if (l == 0)
        __hip_atomic_store(flags + w, t + 1, __ATOMIC_RELAXED, __HIP_MEMORY_SCOPE_AGENT);
    }
    // no second __syncthreads: LDS 'part' is double-buffered; waves pipeline into
    // the next step's poll while wave 0 finalizes.
  }
}

// ---------------- K4: out = W_i2o @ [x_last, h_last] + b ----------------
__global__ __launch_bounds__(256) void k4_out(const float* __restrict__ X,
                                              const float* __restrict__ Wi2o,
                                              const float* __restrict__ bi2o,
                                              const float* __restrict__ hbuf,
                                              float* __restrict__ out) {
  const int v = threadIdx.x >> 6, l = threadIdx.x & 63;
  const int o = blockIdx.x * 4 + v;
  const float* wrow = Wi2o + (long long)o * CONCAT;
  const float* xlast = X + (long long)(SEQ - 1) * IN_DIM;
  const float* hlast = hbuf + (long long)(SEQ - 1) * HID;
  float s = 0.f;
  for (int k = l; k < IN_DIM; k += 64) s = fmaf(wrow[k], xlast[k], s);
  for (int k = l; k < HID; k += 64) s = fmaf(wrow[IN_DIM + k], hlast[k], s);
#pragma unroll
  for (int m = 1; m < 64; m <<= 1) s += __shfl_xor(s, m, 64);
  if (l == 0) out[o] = s + bi2o[o];
}

extern "C" void kernel_launch(void* const* d_in, const int* in_sizes, int n_in,
                              void* d_out, int out_size, void* d_ws, size_t ws_size,
                              hipStream_t stream) {
  (void)in_sizes; (void)n_in; (void)out_size; (void)ws_size;
  const float* X    = (const float*)d_in[0];
  const float* Wi2h = (const float*)d_in[1];
  const float* bi2h = (const float*)d_in[2];
  const float* Wi2o = (const float*)d_in[3];
  const float* bi2o = (const float*)d_in[4];
  float* out = (float*)d_out;

  char* ws = (char*)d_ws;
  float* Z              = (float*)(ws);
  float* hbuf           = (float*)(ws + 33554432);
  __hip_bfloat16* Xb    = (__hip_bfloat16*)(ws + 33554432);  // overlaps hbuf (safe: stream order)
  __hip_bfloat16* Wxb   = (__hip_bfloat16*)(ws + 41943040);
  int* flags            = (int*)(ws + 67108864);

  hipLaunchKernelGGL(k1_prep, dim3(2048), dim3(256), 0, stream, X, Wi2h, Xb, Wxb, flags);
  hipLaunchKernelGGL(k2_zgemm, dim3(2048), dim3(256), 0, stream, Xb, Wxb, bi2h, Z);

  void* args[] = { (void*)&Wi2h, (void*)&Z, (void*)&hbuf, (void*)&flags };
  hipLaunchCooperativeKernel((void*)k3_rnn, dim3(256), dim3(512), args, 0, stream);

  hipLaunchKernelGGL(k4_out, dim3(512), dim3(256), 0, stream, X, Wi2o, bi2o, hbuf, out);
}

// Round 4
// 8234.522 us; speedup vs baseline: 7.0176x; 1.2613x over previous
//
#include <hip/hip_runtime.h>
#include <hip/hip_bf16.h>
#include <stdint.h>

#define SEQ 2048
#define IN_DIM 2048
#define HID 4096
#define CONCAT 6144
#define OUT_DIM 2048

typedef __attribute__((ext_vector_type(8))) short s8v;
typedef __attribute__((ext_vector_type(4))) float f4v;

#define SENT 0xFFFFFFFFu  // sentinel bit pattern; sigmoid output in (0,1) never matches
#define SPIN_BUDGET 100000  // ~3 ms/step; converts a would-be deadlock into absmax failure

// ---------------- ws layout (bytes) ----------------
// Z:     [0, 33554432)            float Z[SEQ][HID]
// hbuf:  [33554432, 67108864)     float hbuf[SEQ][HID]   (rows 1..2047 used)
// Xb:    [33554432, +8388608)     bf16  (overlaps hbuf; dead before memset re-arms sentinel)
// Wxb:   [41943040, +16777216)    bf16
// total required: 67,108,864 B

// ---------------- K1: pack bf16 ----------------
__global__ __launch_bounds__(256) void k1_prep(const float* __restrict__ X,
                                               const float* __restrict__ Wi2h,
                                               __hip_bfloat16* __restrict__ Xb,
                                               __hip_bfloat16* __restrict__ Wxb) {
  int gid = blockIdx.x * blockDim.x + threadIdx.x;
  int stride = gridDim.x * blockDim.x;
  for (int i = gid; i < SEQ * IN_DIM; i += stride)
    Xb[i] = __float2bfloat16(X[i]);
  for (int i = gid; i < HID * IN_DIM; i += stride) {
    int r = i >> 11, c = i & (IN_DIM - 1);
    Wxb[i] = __float2bfloat16(Wi2h[(long long)r * CONCAT + c]);
  }
}

// ---------------- K2: Z = Xb @ Wxb^T + b  (bf16 MFMA, 64x64 tiles) ----------------
__global__ __launch_bounds__(256) void k2_zgemm(const __hip_bfloat16* __restrict__ Xb,
                                                const __hip_bfloat16* __restrict__ Wxb,
                                                const float* __restrict__ bias,
                                                float* __restrict__ Z) {
  __shared__ __align__(16) __hip_bfloat16 As[64][40];  // +8 pad: kills ds_read conflicts
  __shared__ __align__(16) __hip_bfloat16 Bs[64][40];
  const int bm = blockIdx.x & 31;   // 32 M-tiles (SEQ/64)
  const int bn = blockIdx.x >> 5;   // 64 N-tiles (HID/64)
  const int tid = threadIdx.x;
  const int wv = tid >> 6, l = tid & 63;
  const int wr = (wv >> 1) * 32, wc = (wv & 1) * 32;   // wave's 32x32 quadrant
  const int fr = l & 15, fko = (l >> 4) * 8;

  f4v acc[2][2] = {};
  const int r = tid >> 2, cc = (tid & 3) * 8;          // staging: row, 8-elem chunk
  const __hip_bfloat16* ga = Xb + (long long)(bm * 64 + r) * IN_DIM + cc;
  const __hip_bfloat16* gb = Wxb + (long long)(bn * 64 + r) * IN_DIM + cc;

  for (int k0 = 0; k0 < IN_DIM; k0 += 32) {
    *(s8v*)&As[r][cc] = *(const s8v*)(ga + k0);
    *(s8v*)&Bs[r][cc] = *(const s8v*)(gb + k0);
    __syncthreads();
    s8v a0 = *(const s8v*)&As[wr + fr][fko];
    s8v a1 = *(const s8v*)&As[wr + 16 + fr][fko];
    s8v b0 = *(const s8v*)&Bs[wc + fr][fko];
    s8v b1 = *(const s8v*)&Bs[wc + 16 + fr][fko];
    acc[0][0] = __builtin_amdgcn_mfma_f32_16x16x32_bf16(a0, b0, acc[0][0], 0, 0, 0);
    acc[0][1] = __builtin_amdgcn_mfma_f32_16x16x32_bf16(a0, b1, acc[0][1], 0, 0, 0);
    acc[1][0] = __builtin_amdgcn_mfma_f32_16x16x32_bf16(a1, b0, acc[1][0], 0, 0, 0);
    acc[1][1] = __builtin_amdgcn_mfma_f32_16x16x32_bf16(a1, b1, acc[1][1], 0, 0, 0);
    __syncthreads();
  }
#pragma unroll
  for (int fm = 0; fm < 2; ++fm)
#pragma unroll
    for (int fn = 0; fn < 2; ++fn)
#pragma unroll
      for (int i = 0; i < 4; ++i) {
        int row = bm * 64 + wr + fm * 16 + (l >> 4) * 4 + i;
        int col = bn * 64 + wc + fn * 16 + fr;
        Z[(long long)row * HID + col] = acc[fm][fn][i] + bias[col];
      }
}

// ---------------- K3: persistent-weight recurrence (cooperative) ----------------
// 256 WGs x 512 thr. WG w owns h rows [16w,16w+16). Wave v owns K-slice [512v,512v+512).
// Lane l: k indices 512v + 64j + l (j=0..7); weights Wreg[16][8] pinned (AGPR-resident).
// Sync: DATA-AS-FLAG. hbuf pre-armed to SENT each launch; producers store h values
// (relaxed agent atomics, sc1 -> IF$ coherence point) with NO ordering wait; consumers
// poll the h words themselves until non-sentinel. One one-way visibility per step —
// no producer-side vmcnt round trip, no flag-line hotspot. Bounded spin: on timeout
// proceed with sentinel NaNs (-> absmax failure, not a GPU hang).
__global__ __launch_bounds__(512, 1) void k3_rnn(const float* __restrict__ Wi2h,
                                                 const float* __restrict__ Z,
                                                 float* __restrict__ hbuf) {
  const int w = blockIdx.x;
  const int tid = threadIdx.x;
  const int v = tid >> 6;
  const int l = tid & 63;
  const int rowbase = w * 16;
  const int kbase = v * 512 + l;

  float Wreg[16][8];
#pragma unroll
  for (int r = 0; r < 16; ++r) {
    const float* src = Wi2h + (long long)(rowbase + r) * CONCAT + IN_DIM + kbase;
#pragma unroll
    for (int j = 0; j < 8; ++j) Wreg[r][j] = src[64 * j];
  }
  // pin weights: opaque identity so the compiler can neither rematerialize from
  // memory nor sink the loads into the t-loop (it AGPR-spills them — fine)
#pragma unroll
  for (int r = 0; r < 16; ++r)
#pragma unroll
    for (int j = 0; j < 8; ++j)
      asm volatile("" : "+v"(Wreg[r][j]));

  __shared__ float part[2][8][16];
  const int lm = l & 15;
  const int r_mine = ((lm & 1) << 3) | ((lm & 2) << 1) | ((lm & 4) >> 1) | ((lm & 8) >> 3);

  for (int t = 0; t < SEQ - 1; ++t) {
    // prefetch z for this WG's rows (independent of h)
    float zv = 0.f;
    if (v == 0 && l < 16) zv = Z[(long long)t * HID + rowbase + l];

    float acc[16];
#pragma unroll
    for (int r = 0; r < 16; ++r) acc[r] = 0.f;

    if (t > 0) {
      // poll the h data directly (sentinel-armed); per-word drop-out shrinks traffic
      const uint32_t* hrow = (const uint32_t*)hbuf + (long long)t * HID + kbase;
      uint32_t u[8];
      bool got[8];
#pragma unroll
      for (int j = 0; j < 8; ++j) got[j] = false;
      int spins = 0;
      while (true) {
        bool allg = true;
#pragma unroll
        for (int j = 0; j < 8; ++j) {
          if (!got[j]) {
            u[j] = __hip_atomic_load(hrow + 64 * j, __ATOMIC_RELAXED, __HIP_MEMORY_SCOPE_AGENT);
            got[j] = (u[j] != SENT);
          }
          allg &= got[j];
        }
        if (__all(allg)) break;
        if (++spins > SPIN_BUDGET) break;  // deadlock insurance: fail loud, not hang
        __builtin_amdgcn_s_sleep(1);
      }
      float hv[8];
#pragma unroll
      for (int j = 0; j < 8; ++j) hv[j] = __builtin_bit_cast(float, u[j]);
#pragma unroll
      for (int r = 0; r < 16; ++r)
#pragma unroll
        for (int j = 0; j < 8; ++j)
          acc[r] = fmaf(Wreg[r][j], hv[j], acc[r]);
    }

    // reduce-scatter butterfly: 16 accs across 64 lanes -> 1 row-sum per lane-of-16
#pragma unroll
    for (int i = 0; i < 8; ++i) {
      float send = (l & 1) ? acc[i] : acc[i + 8];
      float keep = (l & 1) ? acc[i + 8] : acc[i];
      acc[i] = keep + __shfl_xor(send, 1, 64);
    }
#pragma unroll
    for (int i = 0; i < 4; ++i) {
      float send = (l & 2) ? acc[i] : acc[i + 4];
      float keep = (l & 2) ? acc[i + 4] : acc[i];
      acc[i] = keep + __shfl_xor(send, 2, 64);
    }
#pragma unroll
    for (int i = 0; i < 2; ++i) {
      float send = (l & 4) ? acc[i] : acc[i + 2];
      float keep = (l & 4) ? acc[i + 2] : acc[i];
      acc[i] = keep + __shfl_xor(send, 4, 64);
    }
    {
      float send = (l & 8) ? acc[0] : acc[1];
      float keep = (l & 8) ? acc[1] : acc[0];
      acc[0] = keep + __shfl_xor(send, 8, 64);
    }
    float rsum = acc[0];
    rsum += __shfl_xor(rsum, 16, 64);
    rsum += __shfl_xor(rsum, 32, 64);

    const int b = t & 1;
    if (l < 16) part[b][v][r_mine] = rsum;
    __syncthreads();

    if (v == 0 && l < 16) {
      float s = 0.f;
#pragma unroll
      for (int q = 0; q < 8; ++q) s += part[b][q][l];
      float pre = s + zv;
      float hn = 1.0f / (1.0f + __expf(-pre));
      // store IS the signal — no ordering wait needed
      __hip_atomic_store(hbuf + (long long)(t + 1) * HID + rowbase + l, hn,
                         __ATOMIC_RELAXED, __HIP_MEMORY_SCOPE_AGENT);
    }
    // no second __syncthreads: LDS 'part' is double-buffered; waves pipeline into
    // the next step's poll while wave 0 finalizes.
  }
}

// ---------------- K4: out = W_i2o @ [x_last, h_last] + b ----------------
__global__ __launch_bounds__(256) void k4_out(const float* __restrict__ X,
                                              const float* __restrict__ Wi2o,
                                              const float* __restrict__ bi2o,
                                              const float* __restrict__ hbuf,
                                              float* __restrict__ out) {
  const int v = threadIdx.x >> 6, l = threadIdx.x & 63;
  const int o = blockIdx.x * 4 + v;
  const float* wrow = Wi2o + (long long)o * CONCAT;
  const float* xlast = X + (long long)(SEQ - 1) * IN_DIM;
  const float* hlast = hbuf + (long long)(SEQ - 1) * HID;
  float s = 0.f;
  for (int k = l; k < IN_DIM; k += 64) s = fmaf(wrow[k], xlast[k], s);
  for (int k = l; k < HID; k += 64) s = fmaf(wrow[IN_DIM + k], hlast[k], s);
#pragma unroll
  for (int m = 1; m < 64; m <<= 1) s += __shfl_xor(s, m, 64);
  if (l == 0) out[o] = s + bi2o[o];
}

extern "C" void kernel_launch(void* const* d_in, const int* in_sizes, int n_in,
                              void* d_out, int out_size, void* d_ws, size_t ws_size,
                              hipStream_t stream) {
  (void)in_sizes; (void)n_in; (void)out_size; (void)ws_size;
  const float* X    = (const float*)d_in[0];
  const float* Wi2h = (const float*)d_in[1];
  const float* bi2h = (const float*)d_in[2];
  const float* Wi2o = (const float*)d_in[3];
  const float* bi2o = (const float*)d_in[4];
  float* out = (float*)d_out;

  char* ws = (char*)d_ws;
  float* Z              = (float*)(ws);
  float* hbuf           = (float*)(ws + 33554432);
  __hip_bfloat16* Xb    = (__hip_bfloat16*)(ws + 33554432);  // overlaps hbuf (dead before memset)
  __hip_bfloat16* Wxb   = (__hip_bfloat16*)(ws + 41943040);

  hipLaunchKernelGGL(k1_prep, dim3(2048), dim3(256), 0, stream, X, Wi2h, Xb, Wxb);
  hipLaunchKernelGGL(k2_zgemm, dim3(2048), dim3(256), 0, stream, Xb, Wxb, bi2h, Z);

  // re-arm the data-as-flag sentinel every launch (graph-capture safe, stream-ordered)
  hipMemsetAsync(hbuf, 0xFF, 33554432, stream);

  void* args[] = { (void*)&Wi2h, (void*)&Z, (void*)&hbuf };
  hipLaunchCooperativeKernel((void*)k3_rnn, dim3(256), dim3(512), args, 0, stream);

  hipLaunchKernelGGL(k4_out, dim3(512), dim3(256), 0, stream, X, Wi2o, bi2o, hbuf, out);
}